// Round 1
// baseline (849.608 us; speedup 1.0000x reference)
//
#include <hip/hip_runtime.h>
#include <hip/hip_bf16.h>

#define HDIM 4096
#define DHEAD 128
#define NQH 32
#define NKVH 8
#define SEQ 2048

typedef __bf16 bf16x8 __attribute__((ext_vector_type(8)));
typedef unsigned short ushort8 __attribute__((ext_vector_type(8)));
typedef float f32x4 __attribute__((ext_vector_type(4)));

__device__ inline unsigned short f2bf(float f) {
    unsigned u = __float_as_uint(f);
    u += 0x7fffu + ((u >> 16) & 1u);
    return (unsigned short)(u >> 16);
}

// ---------------- transpose + fp32->bf16 convert: in[K][N] -> out[N][K] ----------------
__global__ void transpose_convert(const float* __restrict__ in, unsigned short* __restrict__ out,
                                  int K, int N) {
    __shared__ float tile[32][33];
    const int n0 = blockIdx.x * 32, k0 = blockIdx.y * 32;
    const int tx = threadIdx.x, ty = threadIdx.y;  // 32 x 8
    for (int r = 0; r < 32; r += 8)
        tile[ty + r][tx] = in[(size_t)(k0 + ty + r) * N + n0 + tx];
    __syncthreads();
    for (int r = 0; r < 32; r += 8)
        out[(size_t)(n0 + ty + r) * K + k0 + tx] = f2bf(tile[tx][ty + r]);
}

// ---------------- LayerNorm: fp32 (S,H) -> bf16 (S,H) ----------------
__global__ __launch_bounds__(256) void layernorm_kernel(
    const float* __restrict__ hs, const float* __restrict__ w, const float* __restrict__ b,
    unsigned short* __restrict__ xb) {
    const int s = blockIdx.x;
    const float* row = hs + (size_t)s * HDIM;
    const int t = threadIdx.x;
    float vals[16];
    float sum = 0.f, sq = 0.f;
    for (int j = 0; j < 16; j++) {
        float v = row[j * 256 + t];
        vals[j] = v; sum += v; sq += v * v;
    }
    for (int off = 1; off < 64; off <<= 1) {
        sum += __shfl_xor(sum, off);
        sq  += __shfl_xor(sq, off);
    }
    __shared__ float ps[4], pq[4];
    if ((t & 63) == 0) { ps[t >> 6] = sum; pq[t >> 6] = sq; }
    __syncthreads();
    sum = ps[0] + ps[1] + ps[2] + ps[3];
    sq  = pq[0] + pq[1] + pq[2] + pq[3];
    const float mu = sum * (1.0f / HDIM);
    const float var = sq * (1.0f / HDIM) - mu * mu;
    const float rs = rsqrtf(var + 1e-5f);
    for (int j = 0; j < 16; j++) {
        int i = j * 256 + t;
        xb[(size_t)s * HDIM + i] = f2bf((vals[j] - mu) * rs * w[i] + b[i]);
    }
}

// ---------------- GEMM: C[M,N] = A[M,K] * Bt[N,K]^T   (bf16 in, fp32 out) ----------------
__global__ __launch_bounds__(256) void gemm_bt(
    const unsigned short* __restrict__ A, const unsigned short* __restrict__ Bt,
    float* __restrict__ C, int M, int N, int K, int nbx) {
    __shared__ __align__(16) unsigned short As[128][32];
    __shared__ __align__(16) unsigned short Bs[128][32];
    const int bx = blockIdx.x % nbx;
    const int by = blockIdx.x / nbx;
    const int row0 = by * 128, col0 = bx * 128;
    const int t = threadIdx.x;
    const int lane = t & 63, wave = t >> 6;
    const int wr = wave >> 1, wc = wave & 1;
    const int r16 = lane & 15, kq = lane >> 4;

    f32x4 acc[4][4] = {};
    const int srow = t >> 1, scol = (t & 1) * 16;
    const size_t abase = (size_t)(row0 + srow) * K + scol;
    const size_t bbase = (size_t)(col0 + srow) * K + scol;

    for (int k0 = 0; k0 < K; k0 += 32) {
        ushort8 a0 = *(const ushort8*)&A[abase + k0];
        ushort8 a1 = *(const ushort8*)&A[abase + k0 + 8];
        ushort8 b0 = *(const ushort8*)&Bt[bbase + k0];
        ushort8 b1 = *(const ushort8*)&Bt[bbase + k0 + 8];
        __syncthreads();
        *(ushort8*)&As[srow][scol]     = a0;
        *(ushort8*)&As[srow][scol + 8] = a1;
        *(ushort8*)&Bs[srow][scol]     = b0;
        *(ushort8*)&Bs[srow][scol + 8] = b1;
        __syncthreads();
        bf16x8 af[4], bfr[4];
        for (int i = 0; i < 4; i++) af[i]  = *(const bf16x8*)&As[wr * 64 + i * 16 + r16][kq * 8];
        for (int j = 0; j < 4; j++) bfr[j] = *(const bf16x8*)&Bs[wc * 64 + j * 16 + r16][kq * 8];
        for (int i = 0; i < 4; i++)
            for (int j = 0; j < 4; j++)
                acc[i][j] = __builtin_amdgcn_mfma_f32_16x16x32_bf16(af[i], bfr[j], acc[i][j], 0, 0, 0);
    }
    for (int i = 0; i < 4; i++)
        for (int j = 0; j < 4; j++)
            for (int r = 0; r < 4; r++) {
                int row = row0 + wr * 64 + i * 16 + kq * 4 + r;
                int col = col0 + wc * 64 + j * 16 + r16;
                C[(size_t)row * N + col] = acc[i][j][r];
            }
}

// ---------------- RoPE + convert to head-major bf16 ----------------
// grid (SEQ, NQH + 2*NKVH), block 64. q gets 1/sqrt(D) folded in.
__global__ void rope_convert(const float* __restrict__ qf, const float* __restrict__ kf,
                             const float* __restrict__ vf, unsigned short* __restrict__ qb,
                             unsigned short* __restrict__ kb, unsigned short* __restrict__ vb) {
    const int s = blockIdx.x;
    const int head = blockIdx.y;
    const int d = threadIdx.x;  // 0..63
    const float SCALE = 0.08838834764831845f;  // 1/sqrt(128)
    if (head < NQH) {
        const float* src = qf + ((size_t)s * NQH + head) * DHEAD;
        float x1 = src[d], x2 = src[d + 64];
        float f = (float)s * (1.0f / powf(10000.0f, (float)d * (1.0f / 64.0f)));
        float c = cosf(f), sn = sinf(f);
        unsigned short* dst = qb + ((size_t)head * SEQ + s) * DHEAD;
        dst[d]      = f2bf((x1 * c - x2 * sn) * SCALE);
        dst[d + 64] = f2bf((x2 * c + x1 * sn) * SCALE);
    } else if (head < NQH + NKVH) {
        const int hk = head - NQH;
        const float* src = kf + ((size_t)s * NKVH + hk) * DHEAD;
        float x1 = src[d], x2 = src[d + 64];
        float f = (float)s * (1.0f / powf(10000.0f, (float)d * (1.0f / 64.0f)));
        float c = cosf(f), sn = sinf(f);
        unsigned short* dst = kb + ((size_t)hk * SEQ + s) * DHEAD;
        dst[d]      = f2bf(x1 * c - x2 * sn);
        dst[d + 64] = f2bf(x2 * c + x1 * sn);
    } else {
        const int hv = head - NQH - NKVH;
        const float* src = vf + ((size_t)s * NKVH + hv) * DHEAD;
        unsigned short* dst = vb + ((size_t)hv * SEQ + s) * DHEAD;
        dst[d]      = f2bf(src[d]);
        dst[d + 64] = f2bf(src[d + 64]);
    }
}

// ---------------- Flash attention: Q[32][S][128], K/V[8][S][128] -> O[S][4096] ----------------
__global__ __launch_bounds__(256) void attention_kernel(
    const unsigned short* __restrict__ Q, const unsigned short* __restrict__ K,
    const unsigned short* __restrict__ V, unsigned short* __restrict__ O) {
    __shared__ __align__(16) unsigned short Ks[32][128];
    __shared__ __align__(16) unsigned short Vt[128][32];
    __shared__ __align__(16) unsigned short Pl[4][16][32];
    const int h = blockIdx.x & 31;
    const int qb = blockIdx.x >> 5;
    const int t = threadIdx.x, lane = t & 63, wave = t >> 6;
    const int r16 = lane & 15, kq = lane >> 4;
    const int q0 = qb * 64 + wave * 16;
    const int hkv = h >> 2;

    bf16x8 qfrag[4];
    const unsigned short* qrow = Q + ((size_t)h * SEQ + q0 + r16) * DHEAD;
    for (int c = 0; c < 4; c++) qfrag[c] = *(const bf16x8*)&qrow[c * 32 + kq * 8];

    f32x4 acc[8] = {};
    float m_r[4], l_r[4];
    for (int r = 0; r < 4; r++) { m_r[r] = -1e30f; l_r[r] = 0.f; }

    const int kbmax = (qb * 64 + 63) >> 5;
    const size_t kvbase = (size_t)hkv * SEQ * DHEAD;
    for (int kb = 0; kb <= kbmax; ++kb) {
        __syncthreads();
        for (int rep = 0; rep < 2; rep++) {
            int idx = rep * 2048 + t * 8;
            int row = idx >> 7, col = idx & 127;
            size_t g = kvbase + (size_t)(kb * 32 + row) * DHEAD + col;
            ushort8 kv = *(const ushort8*)&K[g];
            *(ushort8*)&Ks[row][col] = kv;
            ushort8 vv = *(const ushort8*)&V[g];
            for (int j = 0; j < 8; j++) Vt[col + j][row] = vv[j];
        }
        __syncthreads();
        f32x4 sf[2];
        for (int ct = 0; ct < 2; ct++) {
            f32x4 s4 = {};
            for (int c = 0; c < 4; c++) {
                bf16x8 kf2 = *(const bf16x8*)&Ks[ct * 16 + r16][c * 32 + kq * 8];
                s4 = __builtin_amdgcn_mfma_f32_16x16x32_bf16(qfrag[c], kf2, s4, 0, 0, 0);
            }
            sf[ct] = s4;
        }
        for (int r = 0; r < 4; r++) {
            int qg = q0 + kq * 4 + r;
            for (int ct = 0; ct < 2; ct++) {
                int col = kb * 32 + ct * 16 + r16;
                if (col > qg) sf[ct][r] = -1e30f;
            }
        }
        for (int r = 0; r < 4; r++) {
            float mx = fmaxf(sf[0][r], sf[1][r]);
            for (int off = 1; off < 16; off <<= 1) mx = fmaxf(mx, __shfl_xor(mx, off, 16));
            float mnew = fmaxf(m_r[r], mx);
            float scale = __expf(m_r[r] - mnew);
            float p0 = __expf(sf[0][r] - mnew);
            float p1 = __expf(sf[1][r] - mnew);
            float sum = p0 + p1;
            for (int off = 1; off < 16; off <<= 1) sum += __shfl_xor(sum, off, 16);
            l_r[r] = l_r[r] * scale + sum;
            m_r[r] = mnew;
            sf[0][r] = p0; sf[1][r] = p1;
            for (int nt = 0; nt < 8; nt++) acc[nt][r] *= scale;
        }
        for (int r = 0; r < 4; r++) {
            Pl[wave][kq * 4 + r][r16]      = f2bf(sf[0][r]);
            Pl[wave][kq * 4 + r][16 + r16] = f2bf(sf[1][r]);
        }
        __syncthreads();
        bf16x8 pf = *(const bf16x8*)&Pl[wave][r16][kq * 8];
        for (int nt = 0; nt < 8; nt++) {
            bf16x8 vfr = *(const bf16x8*)&Vt[nt * 16 + r16][kq * 8];
            acc[nt] = __builtin_amdgcn_mfma_f32_16x16x32_bf16(pf, vfr, acc[nt], 0, 0, 0);
        }
    }
    float invl[4];
    for (int r = 0; r < 4; r++) invl[r] = 1.0f / l_r[r];
    for (int nt = 0; nt < 8; nt++)
        for (int r = 0; r < 4; r++)
            O[(size_t)(q0 + kq * 4 + r) * HDIM + h * DHEAD + nt * 16 + r16] =
                f2bf(acc[nt][r] * invl[r]);
}

extern "C" void kernel_launch(void* const* d_in, const int* in_sizes, int n_in,
                              void* d_out, int out_size, void* d_ws, size_t ws_size,
                              hipStream_t stream) {
    const float* hs  = (const float*)d_in[0];
    const float* lnw = (const float*)d_in[1];
    const float* lnb = (const float*)d_in[2];
    const float* wq  = (const float*)d_in[3];
    const float* wk  = (const float*)d_in[4];
    const float* wv  = (const float*)d_in[5];
    const float* wo  = (const float*)d_in[6];
    float* out = (float*)d_out;

    char* ws = (char*)d_ws;
    size_t off = 0;
    auto alloc = [&](size_t bytes) {
        void* p = ws + off;
        off += (bytes + 255) & ~(size_t)255;
        return p;
    };
    unsigned short* xb   = (unsigned short*)alloc((size_t)SEQ * HDIM * 2);
    unsigned short* wqT  = (unsigned short*)alloc((size_t)HDIM * (NQH * DHEAD) * 2);
    unsigned short* wkT  = (unsigned short*)alloc((size_t)HDIM * (NKVH * DHEAD) * 2);
    unsigned short* wvT  = (unsigned short*)alloc((size_t)HDIM * (NKVH * DHEAD) * 2);
    unsigned short* woT  = (unsigned short*)alloc((size_t)(NQH * DHEAD) * HDIM * 2);
    float* qf            = (float*)alloc((size_t)SEQ * NQH * DHEAD * 4);
    float* kf            = (float*)alloc((size_t)SEQ * NKVH * DHEAD * 4);
    float* vf            = (float*)alloc((size_t)SEQ * NKVH * DHEAD * 4);
    unsigned short* qb   = (unsigned short*)alloc((size_t)NQH * SEQ * DHEAD * 2);
    unsigned short* kb   = (unsigned short*)alloc((size_t)NKVH * SEQ * DHEAD * 2);
    unsigned short* vb   = (unsigned short*)alloc((size_t)NKVH * SEQ * DHEAD * 2);
    unsigned short* attnb = (unsigned short*)qf;  // reuse q-fp32 region after RoPE

    dim3 tb(32, 8);
    // weights: in (K=H rows, N cols) -> out (N, K)
    transpose_convert<<<dim3(4096 / 32, 4096 / 32), tb, 0, stream>>>(wq, wqT, 4096, 4096);
    transpose_convert<<<dim3(1024 / 32, 4096 / 32), tb, 0, stream>>>(wk, wkT, 4096, 1024);
    transpose_convert<<<dim3(1024 / 32, 4096 / 32), tb, 0, stream>>>(wv, wvT, 4096, 1024);
    transpose_convert<<<dim3(4096 / 32, 4096 / 32), tb, 0, stream>>>(wo, woT, 4096, 4096);

    layernorm_kernel<<<SEQ, 256, 0, stream>>>(hs, lnw, lnb, xb);

    gemm_bt<<<(2048 / 128) * (4096 / 128), 256, 0, stream>>>(xb, wqT, qf, 2048, 4096, 4096, 4096 / 128);
    gemm_bt<<<(2048 / 128) * (1024 / 128), 256, 0, stream>>>(xb, wkT, kf, 2048, 1024, 4096, 1024 / 128);
    gemm_bt<<<(2048 / 128) * (1024 / 128), 256, 0, stream>>>(xb, wvT, vf, 2048, 1024, 4096, 1024 / 128);

    rope_convert<<<dim3(SEQ, NQH + 2 * NKVH), 64, 0, stream>>>(qf, kf, vf, qb, kb, vb);

    attention_kernel<<<NQH * (SEQ / 64), 256, 0, stream>>>(qb, kb, vb, attnb);

    gemm_bt<<<(2048 / 128) * (4096 / 128), 256, 0, stream>>>(attnb, woT, out, 2048, 4096, 4096, 4096 / 128);
}

// Round 2
// 566.949 us; speedup vs baseline: 1.4986x; 1.4986x over previous
//
#include <hip/hip_runtime.h>
#include <hip/hip_bf16.h>

#define HDIM 4096
#define DHEAD 128
#define NQH 32
#define NKVH 8
#define SEQ 2048

typedef __bf16 bf16x8 __attribute__((ext_vector_type(8)));
typedef unsigned short ushort8 __attribute__((ext_vector_type(8)));
typedef float f32x4 __attribute__((ext_vector_type(4)));

__device__ inline unsigned short f2bf(float f) {
    unsigned u = __float_as_uint(f);
    u += 0x7fffu + ((u >> 16) & 1u);
    return (unsigned short)(u >> 16);
}

__device__ inline void gload16(const void* g, void* l) {
    __builtin_amdgcn_global_load_lds(
        (const __attribute__((address_space(1))) unsigned int*)g,
        (__attribute__((address_space(3))) unsigned int*)l, 16, 0, 0);
}

// ---------------- transpose + fp32->bf16 convert: in[K][N] -> out[N][K] ----------------
__global__ void transpose_convert(const float* __restrict__ in, unsigned short* __restrict__ out,
                                  int K, int N) {
    __shared__ float tile[32][33];
    const int n0 = blockIdx.x * 32, k0 = blockIdx.y * 32;
    const int tx = threadIdx.x, ty = threadIdx.y;  // 32 x 8
    for (int r = 0; r < 32; r += 8)
        tile[ty + r][tx] = in[(size_t)(k0 + ty + r) * N + n0 + tx];
    __syncthreads();
    for (int r = 0; r < 32; r += 8)
        out[(size_t)(n0 + ty + r) * K + k0 + tx] = f2bf(tile[tx][ty + r]);
}

// ---------------- V transpose: fp32 (S, NKVH, D) -> bf16 (NKVH, D, S) ----------------
__global__ void transpose_v(const float* __restrict__ vf, unsigned short* __restrict__ vbt) {
    __shared__ float tile[32][33];
    const int s0 = blockIdx.x * 32, d0 = blockIdx.y * 32, hv = blockIdx.z;
    const int tx = threadIdx.x, ty = threadIdx.y;  // 32 x 8
    for (int r = 0; r < 32; r += 8)
        tile[ty + r][tx] = vf[((size_t)(s0 + ty + r) * NKVH + hv) * DHEAD + d0 + tx];
    __syncthreads();
    for (int r = 0; r < 32; r += 8)
        vbt[((size_t)hv * DHEAD + d0 + ty + r) * SEQ + s0 + tx] = f2bf(tile[tx][ty + r]);
}

// ---------------- LayerNorm: fp32 (S,H) -> bf16 (S,H) ----------------
__global__ __launch_bounds__(256) void layernorm_kernel(
    const float* __restrict__ hs, const float* __restrict__ w, const float* __restrict__ b,
    unsigned short* __restrict__ xb) {
    const int s = blockIdx.x;
    const float* row = hs + (size_t)s * HDIM;
    const int t = threadIdx.x;
    float vals[16];
    float sum = 0.f, sq = 0.f;
    for (int j = 0; j < 16; j++) {
        float v = row[j * 256 + t];
        vals[j] = v; sum += v; sq += v * v;
    }
    for (int off = 1; off < 64; off <<= 1) {
        sum += __shfl_xor(sum, off);
        sq  += __shfl_xor(sq, off);
    }
    __shared__ float ps[4], pq[4];
    if ((t & 63) == 0) { ps[t >> 6] = sum; pq[t >> 6] = sq; }
    __syncthreads();
    sum = ps[0] + ps[1] + ps[2] + ps[3];
    sq  = pq[0] + pq[1] + pq[2] + pq[3];
    const float mu = sum * (1.0f / HDIM);
    const float var = sq * (1.0f / HDIM) - mu * mu;
    const float rs = rsqrtf(var + 1e-5f);
    for (int j = 0; j < 16; j++) {
        int i = j * 256 + t;
        xb[(size_t)s * HDIM + i] = f2bf((vals[j] - mu) * rs * w[i] + b[i]);
    }
}

// ---------------- GEMM: C[M,N] = A[M,K] * Bt[N,K]^T   (bf16 in, fp32 out) ----------------
// m97 structure: 128x128 tile, BK=32, global_load_lds width-16 staging, linear LDS.
__global__ __launch_bounds__(256) void gemm_bt(
    const unsigned short* __restrict__ A, const unsigned short* __restrict__ Bt,
    float* __restrict__ C, int M, int N, int K, int nbx) {
    __shared__ __align__(16) unsigned short As[128 * 32];
    __shared__ __align__(16) unsigned short Bs[128 * 32];
    const int bx = blockIdx.x % nbx;
    const int by = blockIdx.x / nbx;
    const int row0 = by * 128, col0 = bx * 128;
    const int t = threadIdx.x;
    const int lane = t & 63, wave = t >> 6;
    const int wr = wave >> 1, wc = wave & 1;
    const int r16 = lane & 15, kq = lane >> 4;

    // staging: each gload op covers 64 rows x 32 k; wave w handles rows w*16..w*16+15,
    // lane l -> row w*16 + (l>>2), 16B chunk (l&3). LDS dest = base + wave*1024B + l*16B.
    const int srow = wave * 16 + (lane >> 2);
    const int sch = lane & 3;
    const unsigned short* ag0 = A  + (size_t)(row0 + srow) * K + sch * 8;
    const unsigned short* ag1 = A  + (size_t)(row0 + 64 + srow) * K + sch * 8;
    const unsigned short* bg0 = Bt + (size_t)(col0 + srow) * K + sch * 8;
    const unsigned short* bg1 = Bt + (size_t)(col0 + 64 + srow) * K + sch * 8;
    unsigned short* la0 = &As[wave * 512];
    unsigned short* la1 = &As[2048 + wave * 512];
    unsigned short* lb0 = &Bs[wave * 512];
    unsigned short* lb1 = &Bs[2048 + wave * 512];

    f32x4 acc[4][4] = {};
    for (int k0 = 0; k0 < K; k0 += 32) {
        __syncthreads();
        gload16(ag0 + k0, la0);
        gload16(ag1 + k0, la1);
        gload16(bg0 + k0, lb0);
        gload16(bg1 + k0, lb1);
        __syncthreads();
        bf16x8 af[4], bfr[4];
        for (int i = 0; i < 4; i++) af[i]  = *(const bf16x8*)&As[(wr * 64 + i * 16 + r16) * 32 + kq * 8];
        for (int j = 0; j < 4; j++) bfr[j] = *(const bf16x8*)&Bs[(wc * 64 + j * 16 + r16) * 32 + kq * 8];
        for (int i = 0; i < 4; i++)
            for (int j = 0; j < 4; j++)
                acc[i][j] = __builtin_amdgcn_mfma_f32_16x16x32_bf16(af[i], bfr[j], acc[i][j], 0, 0, 0);
    }
    for (int i = 0; i < 4; i++)
        for (int j = 0; j < 4; j++)
            for (int r = 0; r < 4; r++) {
                int row = row0 + wr * 64 + i * 16 + kq * 4 + r;
                int col = col0 + wc * 64 + j * 16 + r16;
                C[(size_t)row * N + col] = acc[i][j][r];
            }
}

// ---------------- RoPE + convert to head-major bf16 ----------------
// grid (SEQ, NQH + NKVH), block 64. q gets 1/sqrt(D) folded in.
__global__ void rope_convert(const float* __restrict__ qf, const float* __restrict__ kf,
                             unsigned short* __restrict__ qb, unsigned short* __restrict__ kb) {
    const int s = blockIdx.x;
    const int head = blockIdx.y;
    const int d = threadIdx.x;  // 0..63
    const float SCALE = 0.08838834764831845f;  // 1/sqrt(128)
    const float NLOG = -0.14391156831212787f;  // -ln(10000)/64
    float f = (float)s * __expf((float)d * NLOG);
    float sn, c;
    __sincosf(f, &sn, &c);
    if (head < NQH) {
        const float* src = qf + ((size_t)s * NQH + head) * DHEAD;
        float x1 = src[d], x2 = src[d + 64];
        unsigned short* dst = qb + ((size_t)head * SEQ + s) * DHEAD;
        dst[d]      = f2bf((x1 * c - x2 * sn) * SCALE);
        dst[d + 64] = f2bf((x2 * c + x1 * sn) * SCALE);
    } else {
        const int hk = head - NQH;
        const float* src = kf + ((size_t)s * NKVH + hk) * DHEAD;
        float x1 = src[d], x2 = src[d + 64];
        unsigned short* dst = kb + ((size_t)hk * SEQ + s) * DHEAD;
        dst[d]      = f2bf(x1 * c - x2 * sn);
        dst[d + 64] = f2bf(x2 * c + x1 * sn);
    }
}

// ---------------- Flash attention ----------------
// Q[32][S][128] bf16, K[8][S][128] bf16, Vt[8][128][S] bf16 -> O[S][4096] bf16
// Block: 4 waves x 16 q-rows = 64 q-rows of one head. KVBLK=64.
// All LDS tiles XOR-swizzled on 16B chunks: chunk' = chunk ^ (row & 7).
__global__ __launch_bounds__(256) void attention_kernel(
    const unsigned short* __restrict__ Q, const unsigned short* __restrict__ K,
    const unsigned short* __restrict__ Vt, unsigned short* __restrict__ O) {
    __shared__ __align__(16) unsigned short Ks[64 * 128];    // [kcol][d], swizzled
    __shared__ __align__(16) unsigned short Vs[128 * 64];    // [d][k], swizzled
    __shared__ __align__(16) unsigned short Pl[4][16 * 64];  // per-wave [qr][k], swizzled
    const int h = blockIdx.x & 31;
    const int qb = (SEQ / 64 - 1) - (blockIdx.x >> 5);  // LPT: longest blocks first
    const int t = threadIdx.x, lane = t & 63, wave = t >> 6;
    const int r16 = lane & 15, kq = lane >> 4;
    const int q0 = qb * 64 + wave * 16;
    const int hkv = h >> 2;

    bf16x8 qfrag[4];
    const unsigned short* qrow = Q + ((size_t)h * SEQ + q0 + r16) * DHEAD;
    for (int c = 0; c < 4; c++) qfrag[c] = *(const bf16x8*)&qrow[c * 32 + kq * 8];

    f32x4 acc[8] = {};
    float m_r[4], l_r[4];
    for (int r = 0; r < 4; r++) { m_r[r] = -1e30f; l_r[r] = 0.f; }

    const unsigned short* Kg = K + (size_t)hkv * SEQ * DHEAD;
    const unsigned short* Vg = Vt + (size_t)hkv * DHEAD * SEQ;
    unsigned short* pw = &Pl[wave][0];

    for (int kb = 0; kb <= qb; ++kb) {
        __syncthreads();
        // stage K: 64 rows x 16 chunks of 16B (coalesced reads, swizzled writes)
        for (int p = 0; p < 4; p++) {
            int id = p * 256 + t;
            int row = id >> 4, c = id & 15;
            ushort8 v = *(const ushort8*)&Kg[(size_t)(kb * 64 + row) * DHEAD + c * 8];
            *(ushort8*)&Ks[row * 128 + ((c ^ (row & 7)) * 8)] = v;
        }
        // stage Vt: 128 rows(d) x 8 chunks of 16B
        for (int p = 0; p < 4; p++) {
            int id = p * 256 + t;
            int row = id >> 3, c = id & 7;
            ushort8 v = *(const ushort8*)&Vg[(size_t)row * SEQ + kb * 64 + c * 8];
            *(ushort8*)&Vs[row * 64 + ((c ^ (row & 7)) * 8)] = v;
        }
        __syncthreads();
        // QK^T: 4 col-tiles x 4 d-steps
        f32x4 sf[4];
        for (int ct = 0; ct < 4; ct++) {
            f32x4 s4 = {};
            int row = ct * 16 + r16;
            for (int c = 0; c < 4; c++) {
                int ch = (c * 4 + kq) ^ (row & 7);
                bf16x8 kf2 = *(const bf16x8*)&Ks[row * 128 + ch * 8];
                s4 = __builtin_amdgcn_mfma_f32_16x16x32_bf16(qfrag[c], kf2, s4, 0, 0, 0);
            }
            sf[ct] = s4;
        }
        // causal mask: only the diagonal block needs it
        if (kb == qb) {
            for (int r = 0; r < 4; r++) {
                int qg = q0 + kq * 4 + r;
                for (int ct = 0; ct < 4; ct++) {
                    int col = kb * 64 + ct * 16 + r16;
                    if (col > qg) sf[ct][r] = -1e30f;
                }
            }
        }
        // online softmax (rows live across lanes sharing kq; reduce over r16 group of 16)
        for (int r = 0; r < 4; r++) {
            float mx = fmaxf(fmaxf(sf[0][r], sf[1][r]), fmaxf(sf[2][r], sf[3][r]));
            for (int off = 1; off < 16; off <<= 1) mx = fmaxf(mx, __shfl_xor(mx, off, 16));
            float mnew = fmaxf(m_r[r], mx);
            float scale = __expf(m_r[r] - mnew);
            float sum = 0.f;
            for (int ct = 0; ct < 4; ct++) {
                float p = __expf(sf[ct][r] - mnew);
                sf[ct][r] = p; sum += p;
            }
            for (int off = 1; off < 16; off <<= 1) sum += __shfl_xor(sum, off, 16);
            l_r[r] = l_r[r] * scale + sum;
            m_r[r] = mnew;
            for (int nt = 0; nt < 8; nt++) acc[nt][r] *= scale;
        }
        // write P to per-wave LDS (same-wave: no barrier, lgkmcnt orders)
        for (int ct = 0; ct < 4; ct++)
            for (int r = 0; r < 4; r++) {
                int prow = kq * 4 + r, col = ct * 16 + r16;
                int ch = (col >> 3) ^ (prow & 7);
                pw[prow * 64 + ch * 8 + (col & 7)] = f2bf(sf[ct][r]);
            }
        // PV: 2 k-steps x 8 d-tiles
        for (int k32 = 0; k32 < 2; k32++) {
            int pch = (k32 * 4 + kq) ^ (r16 & 7);
            bf16x8 pf = *(const bf16x8*)&pw[r16 * 64 + pch * 8];
            for (int nt = 0; nt < 8; nt++) {
                int vrow = nt * 16 + r16;
                int vch = (k32 * 4 + kq) ^ (vrow & 7);
                bf16x8 vfr = *(const bf16x8*)&Vs[vrow * 64 + vch * 8];
                acc[nt] = __builtin_amdgcn_mfma_f32_16x16x32_bf16(pf, vfr, acc[nt], 0, 0, 0);
            }
        }
    }
    float invl[4];
    for (int r = 0; r < 4; r++) invl[r] = 1.0f / l_r[r];
    for (int nt = 0; nt < 8; nt++)
        for (int r = 0; r < 4; r++)
            O[(size_t)(q0 + kq * 4 + r) * HDIM + h * DHEAD + nt * 16 + r16] =
                f2bf(acc[nt][r] * invl[r]);
}

extern "C" void kernel_launch(void* const* d_in, const int* in_sizes, int n_in,
                              void* d_out, int out_size, void* d_ws, size_t ws_size,
                              hipStream_t stream) {
    const float* hs  = (const float*)d_in[0];
    const float* lnw = (const float*)d_in[1];
    const float* lnb = (const float*)d_in[2];
    const float* wq  = (const float*)d_in[3];
    const float* wk  = (const float*)d_in[4];
    const float* wv  = (const float*)d_in[5];
    const float* wo  = (const float*)d_in[6];
    float* out = (float*)d_out;

    char* ws = (char*)d_ws;
    size_t off = 0;
    auto alloc = [&](size_t bytes) {
        void* p = ws + off;
        off += (bytes + 255) & ~(size_t)255;
        return p;
    };
    unsigned short* xb   = (unsigned short*)alloc((size_t)SEQ * HDIM * 2);
    unsigned short* wqT  = (unsigned short*)alloc((size_t)HDIM * (NQH * DHEAD) * 2);
    unsigned short* wkT  = (unsigned short*)alloc((size_t)HDIM * (NKVH * DHEAD) * 2);
    unsigned short* wvT  = (unsigned short*)alloc((size_t)HDIM * (NKVH * DHEAD) * 2);
    unsigned short* woT  = (unsigned short*)alloc((size_t)(NQH * DHEAD) * HDIM * 2);
    float* qf            = (float*)alloc((size_t)SEQ * NQH * DHEAD * 4);
    float* kf            = (float*)alloc((size_t)SEQ * NKVH * DHEAD * 4);
    float* vf            = (float*)alloc((size_t)SEQ * NKVH * DHEAD * 4);
    unsigned short* qbuf = (unsigned short*)alloc((size_t)NQH * SEQ * DHEAD * 2);
    unsigned short* kbuf = (unsigned short*)alloc((size_t)NKVH * SEQ * DHEAD * 2);
    unsigned short* vbt  = (unsigned short*)alloc((size_t)NKVH * DHEAD * SEQ * 2);
    unsigned short* attnb = (unsigned short*)qf;  // reuse q-fp32 region after RoPE

    dim3 tb(32, 8);
    transpose_convert<<<dim3(4096 / 32, 4096 / 32), tb, 0, stream>>>(wq, wqT, 4096, 4096);
    transpose_convert<<<dim3(1024 / 32, 4096 / 32), tb, 0, stream>>>(wk, wkT, 4096, 1024);
    transpose_convert<<<dim3(1024 / 32, 4096 / 32), tb, 0, stream>>>(wv, wvT, 4096, 1024);
    transpose_convert<<<dim3(4096 / 32, 4096 / 32), tb, 0, stream>>>(wo, woT, 4096, 4096);

    layernorm_kernel<<<SEQ, 256, 0, stream>>>(hs, lnw, lnb, xb);

    gemm_bt<<<(2048 / 128) * (4096 / 128), 256, 0, stream>>>(xb, wqT, qf, 2048, 4096, 4096, 4096 / 128);
    gemm_bt<<<(2048 / 128) * (1024 / 128), 256, 0, stream>>>(xb, wkT, kf, 2048, 1024, 4096, 1024 / 128);
    gemm_bt<<<(2048 / 128) * (1024 / 128), 256, 0, stream>>>(xb, wvT, vf, 2048, 1024, 4096, 1024 / 128);

    rope_convert<<<dim3(SEQ, NQH + NKVH), 64, 0, stream>>>(qf, kf, qbuf, kbuf);
    transpose_v<<<dim3(SEQ / 32, DHEAD / 32, NKVH), tb, 0, stream>>>(vf, vbt);

    attention_kernel<<<NQH * (SEQ / 64), 256, 0, stream>>>(qbuf, kbuf, vbt, attnb);

    gemm_bt<<<(2048 / 128) * (4096 / 128), 256, 0, stream>>>(attnb, woT, out, 2048, 4096, 4096, 4096 / 128);
}

// Round 3
// 441.168 us; speedup vs baseline: 1.9258x; 1.2851x over previous
//
#include <hip/hip_runtime.h>
#include <hip/hip_bf16.h>

#define HDIM 4096
#define DHEAD 128
#define NQH 32
#define NKVH 8
#define SEQ 2048
#define QKVN 6144  // fused N = 4096 + 1024 + 1024

typedef __bf16 bf16x8 __attribute__((ext_vector_type(8)));
typedef unsigned short ushort8 __attribute__((ext_vector_type(8)));
typedef float f32x4 __attribute__((ext_vector_type(4)));

// wait until <= N vector-memory ops outstanding (lgkm/exp not waited)
#define WAIT_VM(N) __builtin_amdgcn_s_waitcnt(0xF70 | (N))

__device__ inline unsigned short f2bf(float f) {
    unsigned u = __float_as_uint(f);
    u += 0x7fffu + ((u >> 16) & 1u);
    return (unsigned short)(u >> 16);
}

__device__ inline void gload16(const void* g, void* l) {
    __builtin_amdgcn_global_load_lds(
        (const __attribute__((address_space(1))) unsigned int*)g,
        (__attribute__((address_space(3))) unsigned int*)l, 16, 0, 0);
}

// ---------------- transpose + fp32->bf16 convert: in[K][N] -> out[N][K] ----------------
__global__ void transpose_convert(const float* __restrict__ in, unsigned short* __restrict__ out,
                                  int K, int N) {
    __shared__ float tile[32][33];
    const int n0 = blockIdx.x * 32, k0 = blockIdx.y * 32;
    const int tx = threadIdx.x, ty = threadIdx.y;  // 32 x 8
    for (int r = 0; r < 32; r += 8)
        tile[ty + r][tx] = in[(size_t)(k0 + ty + r) * N + n0 + tx];
    __syncthreads();
    for (int r = 0; r < 32; r += 8)
        out[(size_t)(n0 + ty + r) * K + k0 + tx] = f2bf(tile[tx][ty + r]);
}

// ---------------- V transpose: fp32 qkv-fused row -> bf16 (NKVH, D, S) ----------------
__global__ void transpose_v(const float* __restrict__ qkvf, unsigned short* __restrict__ vbt) {
    __shared__ float tile[32][33];
    const int s0 = blockIdx.x * 32, d0 = blockIdx.y * 32, hv = blockIdx.z;
    const int tx = threadIdx.x, ty = threadIdx.y;  // 32 x 8
    for (int r = 0; r < 32; r += 8)
        tile[ty + r][tx] = qkvf[(size_t)(s0 + ty + r) * QKVN + 5120 + hv * DHEAD + d0 + tx];
    __syncthreads();
    for (int r = 0; r < 32; r += 8)
        vbt[((size_t)hv * DHEAD + d0 + ty + r) * SEQ + s0 + tx] = f2bf(tile[tx][ty + r]);
}

// ---------------- LayerNorm: fp32 (S,H) -> bf16 (S,H) ----------------
__global__ __launch_bounds__(256) void layernorm_kernel(
    const float* __restrict__ hs, const float* __restrict__ w, const float* __restrict__ b,
    unsigned short* __restrict__ xb) {
    const int s = blockIdx.x;
    const float* row = hs + (size_t)s * HDIM;
    const int t = threadIdx.x;
    float vals[16];
    float sum = 0.f, sq = 0.f;
    for (int j = 0; j < 16; j++) {
        float v = row[j * 256 + t];
        vals[j] = v; sum += v; sq += v * v;
    }
    for (int off = 1; off < 64; off <<= 1) {
        sum += __shfl_xor(sum, off);
        sq  += __shfl_xor(sq, off);
    }
    __shared__ float ps[4], pq[4];
    if ((t & 63) == 0) { ps[t >> 6] = sum; pq[t >> 6] = sq; }
    __syncthreads();
    sum = ps[0] + ps[1] + ps[2] + ps[3];
    sq  = pq[0] + pq[1] + pq[2] + pq[3];
    const float mu = sum * (1.0f / HDIM);
    const float var = sq * (1.0f / HDIM) - mu * mu;
    const float rs = rsqrtf(var + 1e-5f);
    for (int j = 0; j < 16; j++) {
        int i = j * 256 + t;
        xb[(size_t)s * HDIM + i] = f2bf((vals[j] - mu) * rs * w[i] + b[i]);
    }
}

// ---------------- Pipelined GEMM: C[M,N] = A[M,K] * Bt[N,K]^T (bf16 in, fp32 out) ----------------
// BM=256, BN=128, BK=32. 8 waves (2M x 4N), wave tile 128x32 (8x2 frags).
// 3 LDS buffers; staging runs 2 K-tiles ahead; boundary wait = vmcnt(3) (counted, never 0
// in steady state). T2 swizzle: global source pre-swizzled chunk^= (row>>1)&3, linear LDS
// dest (global_load_lds), swizzled ds_read. T5 setprio around MFMA clusters.
__global__ __launch_bounds__(512, 2) void gemm_pipe(
    const unsigned short* __restrict__ A, const unsigned short* __restrict__ Bt,
    float* __restrict__ C, int M, int N, int K, int nbx) {
    constexpr int BM = 256, BN = 128, BK = 32;
    __shared__ __align__(16) unsigned short Abuf[3][BM * BK];  // 48 KB
    __shared__ __align__(16) unsigned short Bbuf[3][BN * BK];  // 24 KB
    const int bx = blockIdx.x % nbx, by = blockIdx.x / nbx;
    const int row0 = by * BM, col0 = bx * BN;
    const int t = threadIdx.x, lane = t & 63, w = t >> 6;
    const int wr = w >> 2, wc = w & 3;          // 2M x 4N wave grid
    const int r16 = lane & 15, kq = lane >> 4;
    const int lrow = lane >> 2, lch = lane & 3; // staging: 4 lanes per 64B row

    const int NT = K / BK;

    // staging global pointers (pre-swizzled chunk within each 64B k-tile row segment)
    const int ar0 = (w * 2 + 0) * 16 + lrow;
    const int ar1 = (w * 2 + 1) * 16 + lrow;
    const int br  = w * 16 + lrow;
    const unsigned short* agp0 = A  + (size_t)(row0 + ar0) * K + (lch ^ ((ar0 >> 1) & 3)) * 8;
    const unsigned short* agp1 = A  + (size_t)(row0 + ar1) * K + (lch ^ ((ar1 >> 1) & 3)) * 8;
    const unsigned short* bgp  = Bt + (size_t)(col0 + br)  * K + (lch ^ ((br  >> 1) & 3)) * 8;

    // prologue: stage K-tiles 0 and 1 (issue order matters for vmcnt accounting)
    gload16(agp0, &Abuf[0][(w * 2 + 0) * 512]);
    gload16(agp1, &Abuf[0][(w * 2 + 1) * 512]);
    gload16(bgp,  &Bbuf[0][w * 512]);
    gload16(agp0 + BK, &Abuf[1][(w * 2 + 0) * 512]);
    gload16(agp1 + BK, &Abuf[1][(w * 2 + 1) * 512]);
    gload16(bgp  + BK, &Bbuf[1][w * 512]);
    WAIT_VM(3);  // K-tile 0 landed; K-tile 1's 3 in flight
    __builtin_amdgcn_s_barrier();

    f32x4 acc[8][2] = {};
    for (int kt = 0; kt < NT; ++kt) {
        const int cur = kt % 3, nx2 = (kt + 2) % 3;
        const bool pf = (kt + 2) < NT;
        const int koff = (kt + 2) * BK;
        const unsigned short* Ac = &Abuf[cur][0];
        const unsigned short* Bc = &Bbuf[cur][0];

        if (pf) gload16(agp0 + koff, &Abuf[nx2][(w * 2 + 0) * 512]);

        bf16x8 bfr[2];
        #pragma unroll
        for (int j = 0; j < 2; j++) {
            int brow = wc * 32 + j * 16 + r16;
            bfr[j] = *(const bf16x8*)&Bc[brow * BK + (kq ^ ((brow >> 1) & 3)) * 8];
        }
        bf16x8 alo[4];
        #pragma unroll
        for (int i = 0; i < 4; i++) {
            int arow = wr * 128 + i * 16 + r16;
            alo[i] = *(const bf16x8*)&Ac[arow * BK + (kq ^ ((arow >> 1) & 3)) * 8];
        }
        __builtin_amdgcn_s_setprio(1);
        #pragma unroll
        for (int i = 0; i < 4; i++)
            #pragma unroll
            for (int j = 0; j < 2; j++)
                acc[i][j] = __builtin_amdgcn_mfma_f32_16x16x32_bf16(alo[i], bfr[j], acc[i][j], 0, 0, 0);
        __builtin_amdgcn_s_setprio(0);

        if (pf) {
            gload16(agp1 + koff, &Abuf[nx2][(w * 2 + 1) * 512]);
            gload16(bgp  + koff, &Bbuf[nx2][w * 512]);
        }
        bf16x8 ahi[4];
        #pragma unroll
        for (int i = 0; i < 4; i++) {
            int arow = wr * 128 + (4 + i) * 16 + r16;
            ahi[i] = *(const bf16x8*)&Ac[arow * BK + (kq ^ ((arow >> 1) & 3)) * 8];
        }
        __builtin_amdgcn_s_setprio(1);
        #pragma unroll
        for (int i = 0; i < 4; i++)
            #pragma unroll
            for (int j = 0; j < 2; j++)
                acc[4 + i][j] = __builtin_amdgcn_mfma_f32_16x16x32_bf16(ahi[i], bfr[j], acc[4 + i][j], 0, 0, 0);
        __builtin_amdgcn_s_setprio(0);

        // K-tile boundary: counted wait (tile kt+1 landed; kt+2's 3 still in flight)
        if (pf) WAIT_VM(3); else WAIT_VM(0);
        __builtin_amdgcn_s_barrier();
    }

    #pragma unroll
    for (int i = 0; i < 8; i++)
        #pragma unroll
        for (int j = 0; j < 2; j++)
            #pragma unroll
            for (int r = 0; r < 4; r++) {
                int row = row0 + wr * 128 + i * 16 + kq * 4 + r;
                int col = col0 + wc * 32 + j * 16 + r16;
                C[(size_t)row * N + col] = acc[i][j][r];
            }
}

// ---------------- RoPE + convert to head-major bf16 (reads fused qkv fp32) ----------------
__global__ void rope_convert(const float* __restrict__ qkvf,
                             unsigned short* __restrict__ qb, unsigned short* __restrict__ kb) {
    const int s = blockIdx.x;
    const int head = blockIdx.y;
    const int d = threadIdx.x;  // 0..63
    const float SCALE = 0.08838834764831845f;  // 1/sqrt(128)
    const float NLOG = -0.14391156831212787f;  // -ln(10000)/64
    float f = (float)s * __expf((float)d * NLOG);
    float sn, c;
    __sincosf(f, &sn, &c);
    if (head < NQH) {
        const float* src = qkvf + (size_t)s * QKVN + head * DHEAD;
        float x1 = src[d], x2 = src[d + 64];
        unsigned short* dst = qb + ((size_t)head * SEQ + s) * DHEAD;
        dst[d]      = f2bf((x1 * c - x2 * sn) * SCALE);
        dst[d + 64] = f2bf((x2 * c + x1 * sn) * SCALE);
    } else {
        const int hk = head - NQH;
        const float* src = qkvf + (size_t)s * QKVN + 4096 + hk * DHEAD;
        float x1 = src[d], x2 = src[d + 64];
        unsigned short* dst = kb + ((size_t)hk * SEQ + s) * DHEAD;
        dst[d]      = f2bf(x1 * c - x2 * sn);
        dst[d + 64] = f2bf(x2 * c + x1 * sn);
    }
}

// ---------------- Flash attention ----------------
__global__ __launch_bounds__(256) void attention_kernel(
    const unsigned short* __restrict__ Q, const unsigned short* __restrict__ K,
    const unsigned short* __restrict__ Vt, unsigned short* __restrict__ O) {
    __shared__ __align__(16) unsigned short Ks[64 * 128];    // [kcol][d], swizzled
    __shared__ __align__(16) unsigned short Vs[128 * 64];    // [d][k], swizzled
    __shared__ __align__(16) unsigned short Pl[4][16 * 64];  // per-wave [qr][k], swizzled
    const int h = blockIdx.x & 31;
    const int qb = (SEQ / 64 - 1) - (blockIdx.x >> 5);  // LPT: longest blocks first
    const int t = threadIdx.x, lane = t & 63, wave = t >> 6;
    const int r16 = lane & 15, kq = lane >> 4;
    const int q0 = qb * 64 + wave * 16;
    const int hkv = h >> 2;

    bf16x8 qfrag[4];
    const unsigned short* qrow = Q + ((size_t)h * SEQ + q0 + r16) * DHEAD;
    for (int c = 0; c < 4; c++) qfrag[c] = *(const bf16x8*)&qrow[c * 32 + kq * 8];

    f32x4 acc[8] = {};
    float m_r[4], l_r[4];
    for (int r = 0; r < 4; r++) { m_r[r] = -1e30f; l_r[r] = 0.f; }

    const unsigned short* Kg = K + (size_t)hkv * SEQ * DHEAD;
    const unsigned short* Vg = Vt + (size_t)hkv * DHEAD * SEQ;
    unsigned short* pw = &Pl[wave][0];

    for (int kb = 0; kb <= qb; ++kb) {
        __syncthreads();
        for (int p = 0; p < 4; p++) {
            int id = p * 256 + t;
            int row = id >> 4, c = id & 15;
            ushort8 v = *(const ushort8*)&Kg[(size_t)(kb * 64 + row) * DHEAD + c * 8];
            *(ushort8*)&Ks[row * 128 + ((c ^ (row & 7)) * 8)] = v;
        }
        for (int p = 0; p < 4; p++) {
            int id = p * 256 + t;
            int row = id >> 3, c = id & 7;
            ushort8 v = *(const ushort8*)&Vg[(size_t)row * SEQ + kb * 64 + c * 8];
            *(ushort8*)&Vs[row * 64 + ((c ^ (row & 7)) * 8)] = v;
        }
        __syncthreads();
        f32x4 sf[4];
        for (int ct = 0; ct < 4; ct++) {
            f32x4 s4 = {};
            int row = ct * 16 + r16;
            for (int c = 0; c < 4; c++) {
                int ch = (c * 4 + kq) ^ (row & 7);
                bf16x8 kf2 = *(const bf16x8*)&Ks[row * 128 + ch * 8];
                s4 = __builtin_amdgcn_mfma_f32_16x16x32_bf16(qfrag[c], kf2, s4, 0, 0, 0);
            }
            sf[ct] = s4;
        }
        if (kb == qb) {
            for (int r = 0; r < 4; r++) {
                int qg = q0 + kq * 4 + r;
                for (int ct = 0; ct < 4; ct++) {
                    int col = kb * 64 + ct * 16 + r16;
                    if (col > qg) sf[ct][r] = -1e30f;
                }
            }
        }
        for (int r = 0; r < 4; r++) {
            float mx = fmaxf(fmaxf(sf[0][r], sf[1][r]), fmaxf(sf[2][r], sf[3][r]));
            for (int off = 1; off < 16; off <<= 1) mx = fmaxf(mx, __shfl_xor(mx, off, 16));
            float mnew = fmaxf(m_r[r], mx);
            float scale = __expf(m_r[r] - mnew);
            float sum = 0.f;
            for (int ct = 0; ct < 4; ct++) {
                float p = __expf(sf[ct][r] - mnew);
                sf[ct][r] = p; sum += p;
            }
            for (int off = 1; off < 16; off <<= 1) sum += __shfl_xor(sum, off, 16);
            l_r[r] = l_r[r] * scale + sum;
            m_r[r] = mnew;
            for (int nt = 0; nt < 8; nt++) acc[nt][r] *= scale;
        }
        for (int ct = 0; ct < 4; ct++)
            for (int r = 0; r < 4; r++) {
                int prow = kq * 4 + r, col = ct * 16 + r16;
                int ch = (col >> 3) ^ (prow & 7);
                pw[prow * 64 + ch * 8 + (col & 7)] = f2bf(sf[ct][r]);
            }
        for (int k32 = 0; k32 < 2; k32++) {
            int pch = (k32 * 4 + kq) ^ (r16 & 7);
            bf16x8 pf = *(const bf16x8*)&pw[r16 * 64 + pch * 8];
            for (int nt = 0; nt < 8; nt++) {
                int vrow = nt * 16 + r16;
                int vch = (k32 * 4 + kq) ^ (vrow & 7);
                bf16x8 vfr = *(const bf16x8*)&Vs[vrow * 64 + vch * 8];
                acc[nt] = __builtin_amdgcn_mfma_f32_16x16x32_bf16(pf, vfr, acc[nt], 0, 0, 0);
            }
        }
    }
    float invl[4];
    for (int r = 0; r < 4; r++) invl[r] = 1.0f / l_r[r];
    for (int nt = 0; nt < 8; nt++)
        for (int r = 0; r < 4; r++)
            O[(size_t)(q0 + kq * 4 + r) * HDIM + h * DHEAD + nt * 16 + r16] =
                f2bf(acc[nt][r] * invl[r]);
}

extern "C" void kernel_launch(void* const* d_in, const int* in_sizes, int n_in,
                              void* d_out, int out_size, void* d_ws, size_t ws_size,
                              hipStream_t stream) {
    const float* hs  = (const float*)d_in[0];
    const float* lnw = (const float*)d_in[1];
    const float* lnb = (const float*)d_in[2];
    const float* wq  = (const float*)d_in[3];
    const float* wk  = (const float*)d_in[4];
    const float* wv  = (const float*)d_in[5];
    const float* wo  = (const float*)d_in[6];
    float* out = (float*)d_out;

    char* ws = (char*)d_ws;
    size_t off = 0;
    auto alloc = [&](size_t bytes) {
        void* p = ws + off;
        off += (bytes + 255) & ~(size_t)255;
        return p;
    };
    unsigned short* xb   = (unsigned short*)alloc((size_t)SEQ * HDIM * 2);
    // wqT/wkT/wvT contiguous -> fused [6144][4096] B matrix
    unsigned short* wqT  = (unsigned short*)alloc((size_t)HDIM * (NQH * DHEAD) * 2);
    unsigned short* wkT  = (unsigned short*)alloc((size_t)HDIM * (NKVH * DHEAD) * 2);
    unsigned short* wvT  = (unsigned short*)alloc((size_t)HDIM * (NKVH * DHEAD) * 2);
    unsigned short* woT  = (unsigned short*)alloc((size_t)(NQH * DHEAD) * HDIM * 2);
    float* qkvf          = (float*)alloc((size_t)SEQ * QKVN * 4);
    unsigned short* qbuf = (unsigned short*)alloc((size_t)NQH * SEQ * DHEAD * 2);
    unsigned short* kbuf = (unsigned short*)alloc((size_t)NKVH * SEQ * DHEAD * 2);
    unsigned short* vbt  = (unsigned short*)alloc((size_t)NKVH * DHEAD * SEQ * 2);
    unsigned short* attnb = (unsigned short*)qkvf;  // reuse fused-fp32 region after rope/v-transpose

    dim3 tb(32, 8);
    transpose_convert<<<dim3(4096 / 32, 4096 / 32), tb, 0, stream>>>(wq, wqT, 4096, 4096);
    transpose_convert<<<dim3(1024 / 32, 4096 / 32), tb, 0, stream>>>(wk, wkT, 4096, 1024);
    transpose_convert<<<dim3(1024 / 32, 4096 / 32), tb, 0, stream>>>(wv, wvT, 4096, 1024);
    transpose_convert<<<dim3(4096 / 32, 4096 / 32), tb, 0, stream>>>(wo, woT, 4096, 4096);

    layernorm_kernel<<<SEQ, 256, 0, stream>>>(hs, lnw, lnb, xb);

    // fused QKV projection: [2048][4096] x [6144][4096]^T -> [2048][6144]
    gemm_pipe<<<(2048 / 256) * (QKVN / 128), 512, 0, stream>>>(xb, wqT, qkvf, 2048, QKVN, 4096, QKVN / 128);

    rope_convert<<<dim3(SEQ, NQH + NKVH), 64, 0, stream>>>(qkvf, qbuf, kbuf);
    transpose_v<<<dim3(SEQ / 32, DHEAD / 32, NKVH), tb, 0, stream>>>(qkvf, vbt);

    attention_kernel<<<NQH * (SEQ / 64), 256, 0, stream>>>(qbuf, kbuf, vbt, attnb);

    gemm_pipe<<<(2048 / 256) * (4096 / 128), 512, 0, stream>>>(attnb, woT, out, 2048, 4096, 4096, 4096 / 128);
}

// Round 4
// 431.471 us; speedup vs baseline: 1.9691x; 1.0225x over previous
//
#include <hip/hip_runtime.h>
#include <hip/hip_bf16.h>

#define HDIM 4096
#define DHEAD 128
#define NQH 32
#define NKVH 8
#define SEQ 2048
#define QKVN 6144  // fused N = 4096 + 1024 + 1024

typedef __bf16 bf16x8 __attribute__((ext_vector_type(8)));
typedef unsigned short ushort8 __attribute__((ext_vector_type(8)));
typedef float f32x4 __attribute__((ext_vector_type(4)));

// wait until <= N vector-memory ops outstanding (lgkm/exp not waited)
#define WAIT_VM(N) __builtin_amdgcn_s_waitcnt(0xF70 | (N))

__device__ inline unsigned short f2bf(float f) {
    unsigned u = __float_as_uint(f);
    u += 0x7fffu + ((u >> 16) & 1u);
    return (unsigned short)(u >> 16);
}

__device__ inline void gload16(const void* g, void* l) {
    __builtin_amdgcn_global_load_lds(
        (const __attribute__((address_space(1))) unsigned int*)g,
        (__attribute__((address_space(3))) unsigned int*)l, 16, 0, 0);
}

// ---------------- transpose + fp32->bf16 convert: in[K][N] -> out[N][K] ----------------
__global__ void transpose_convert(const float* __restrict__ in, unsigned short* __restrict__ out,
                                  int K, int N) {
    __shared__ float tile[32][33];
    const int n0 = blockIdx.x * 32, k0 = blockIdx.y * 32;
    const int tx = threadIdx.x, ty = threadIdx.y;  // 32 x 8
    for (int r = 0; r < 32; r += 8)
        tile[ty + r][tx] = in[(size_t)(k0 + ty + r) * N + n0 + tx];
    __syncthreads();
    for (int r = 0; r < 32; r += 8)
        out[(size_t)(n0 + ty + r) * K + k0 + tx] = f2bf(tile[tx][ty + r]);
}

// ---------------- V transpose: fp32 qkv-fused row -> bf16 (NKVH, D, S) ----------------
__global__ void transpose_v(const float* __restrict__ qkvf, unsigned short* __restrict__ vbt) {
    __shared__ float tile[32][33];
    const int s0 = blockIdx.x * 32, d0 = blockIdx.y * 32, hv = blockIdx.z;
    const int tx = threadIdx.x, ty = threadIdx.y;  // 32 x 8
    for (int r = 0; r < 32; r += 8)
        tile[ty + r][tx] = qkvf[(size_t)(s0 + ty + r) * QKVN + 5120 + hv * DHEAD + d0 + tx];
    __syncthreads();
    for (int r = 0; r < 32; r += 8)
        vbt[((size_t)hv * DHEAD + d0 + ty + r) * SEQ + s0 + tx] = f2bf(tile[tx][ty + r]);
}

// ---------------- LayerNorm: fp32 (S,H) -> bf16 (S,H) ----------------
__global__ __launch_bounds__(256) void layernorm_kernel(
    const float* __restrict__ hs, const float* __restrict__ w, const float* __restrict__ b,
    unsigned short* __restrict__ xb) {
    const int s = blockIdx.x;
    const float* row = hs + (size_t)s * HDIM;
    const int t = threadIdx.x;
    float vals[16];
    float sum = 0.f, sq = 0.f;
    for (int j = 0; j < 16; j++) {
        float v = row[j * 256 + t];
        vals[j] = v; sum += v; sq += v * v;
    }
    for (int off = 1; off < 64; off <<= 1) {
        sum += __shfl_xor(sum, off);
        sq  += __shfl_xor(sq, off);
    }
    __shared__ float ps[4], pq[4];
    if ((t & 63) == 0) { ps[t >> 6] = sum; pq[t >> 6] = sq; }
    __syncthreads();
    sum = ps[0] + ps[1] + ps[2] + ps[3];
    sq  = pq[0] + pq[1] + pq[2] + pq[3];
    const float mu = sum * (1.0f / HDIM);
    const float var = sq * (1.0f / HDIM) - mu * mu;
    const float rs = rsqrtf(var + 1e-5f);
    for (int j = 0; j < 16; j++) {
        int i = j * 256 + t;
        xb[(size_t)s * HDIM + i] = f2bf((vals[j] - mu) * rs * w[i] + b[i]);
    }
}

// ---------------- Pipelined GEMM: C[M,N] = A[M,K] * Bt[N,K]^T (bf16 in, fp32 out) ----------------
// BM=BN=128, BK=32, 256 threads (4 waves, 2x2), 3 LDS buffers (48KB -> 3 blocks/CU),
// 2-tiles-ahead prefetch, boundary wait vmcnt(4) (counted, never drained mid-loop),
// raw s_barrier, read-side XOR swizzle chunk^((row>>1)&3) with pre-swizzled global source.
__global__ __launch_bounds__(256, 3) void gemm128(
    const unsigned short* __restrict__ A, const unsigned short* __restrict__ Bt,
    float* __restrict__ C, int M, int N, int K, int nbx) {
    constexpr int BK = 32;
    __shared__ __align__(16) unsigned short Abuf[3][128 * BK];
    __shared__ __align__(16) unsigned short Bbuf[3][128 * BK];
    // XCD-chunked bijective swizzle (gridDim.x % 8 == 0)
    const int nwg = gridDim.x;
    const int swz = (blockIdx.x & 7) * (nwg >> 3) + (blockIdx.x >> 3);
    const int bx = swz % nbx, by = swz / nbx;
    const int row0 = by * 128, col0 = bx * 128;
    const int t = threadIdx.x, lane = t & 63, w = t >> 6;
    const int wr = w >> 1, wc = w & 1;
    const int r16 = lane & 15, kq = lane >> 4;
    const int lrow = lane >> 2, lch = lane & 3;  // staging: 4 lanes per 64B row

    const int NT = K / BK;

    // staging rows: instr s in {0,1}: rows s*64 + w*16 .. +15 (lane>>2), chunk pre-swizzled
    const int ar0 = w * 16 + lrow, ar1 = 64 + w * 16 + lrow;
    const unsigned short* agp0 = A  + (size_t)(row0 + ar0) * K + (lch ^ ((ar0 >> 1) & 3)) * 8;
    const unsigned short* agp1 = A  + (size_t)(row0 + ar1) * K + (lch ^ ((ar1 >> 1) & 3)) * 8;
    const unsigned short* bgp0 = Bt + (size_t)(col0 + ar0) * K + (lch ^ ((ar0 >> 1) & 3)) * 8;
    const unsigned short* bgp1 = Bt + (size_t)(col0 + ar1) * K + (lch ^ ((ar1 >> 1) & 3)) * 8;

    // prologue: stage K-tiles 0 and 1
    gload16(agp0, &Abuf[0][w * 512]);
    gload16(agp1, &Abuf[0][2048 + w * 512]);
    gload16(bgp0, &Bbuf[0][w * 512]);
    gload16(bgp1, &Bbuf[0][2048 + w * 512]);
    gload16(agp0 + BK, &Abuf[1][w * 512]);
    gload16(agp1 + BK, &Abuf[1][2048 + w * 512]);
    gload16(bgp0 + BK, &Bbuf[1][w * 512]);
    gload16(bgp1 + BK, &Bbuf[1][2048 + w * 512]);
    WAIT_VM(4);  // K-tile 0 landed; K-tile 1's 4 in flight
    __builtin_amdgcn_s_barrier();

    f32x4 acc[4][4] = {};
    for (int kt = 0; kt < NT; ++kt) {
        const int cur = kt % 3, nx2 = (kt + 2) % 3;
        const bool pf = (kt + 2) < NT;
        const int koff = (kt + 2) * BK;
        const unsigned short* Ac = &Abuf[cur][0];
        const unsigned short* Bc = &Bbuf[cur][0];

        if (pf) {
            gload16(agp0 + koff, &Abuf[nx2][w * 512]);
            gload16(agp1 + koff, &Abuf[nx2][2048 + w * 512]);
        }
        bf16x8 af[4], bfr[4];
        #pragma unroll
        for (int i = 0; i < 4; i++) {
            int arow = wr * 64 + i * 16 + r16;
            af[i] = *(const bf16x8*)&Ac[arow * BK + (kq ^ ((arow >> 1) & 3)) * 8];
        }
        if (pf) {
            gload16(bgp0 + koff, &Bbuf[nx2][w * 512]);
            gload16(bgp1 + koff, &Bbuf[nx2][2048 + w * 512]);
        }
        #pragma unroll
        for (int j = 0; j < 4; j++) {
            int brow = wc * 64 + j * 16 + r16;
            bfr[j] = *(const bf16x8*)&Bc[brow * BK + (kq ^ ((brow >> 1) & 3)) * 8];
        }
        __builtin_amdgcn_s_setprio(1);
        #pragma unroll
        for (int i = 0; i < 4; i++)
            #pragma unroll
            for (int j = 0; j < 4; j++)
                acc[i][j] = __builtin_amdgcn_mfma_f32_16x16x32_bf16(af[i], bfr[j], acc[i][j], 0, 0, 0);
        __builtin_amdgcn_s_setprio(0);

        if (pf) WAIT_VM(4); else WAIT_VM(0);
        __builtin_amdgcn_s_barrier();
    }

    #pragma unroll
    for (int i = 0; i < 4; i++)
        #pragma unroll
        for (int j = 0; j < 4; j++)
            #pragma unroll
            for (int r = 0; r < 4; r++) {
                int row = row0 + wr * 64 + i * 16 + kq * 4 + r;
                int col = col0 + wc * 64 + j * 16 + r16;
                C[(size_t)row * N + col] = acc[i][j][r];
            }
}

// ---------------- RoPE + convert to head-major bf16 (reads fused qkv fp32) ----------------
__global__ void rope_convert(const float* __restrict__ qkvf,
                             unsigned short* __restrict__ qb, unsigned short* __restrict__ kb) {
    const int s = blockIdx.x;
    const int head = blockIdx.y;
    const int d = threadIdx.x;  // 0..63
    const float SCALE = 0.08838834764831845f;  // 1/sqrt(128)
    const float NLOG = -0.14391156831212787f;  // -ln(10000)/64
    float f = (float)s * __expf((float)d * NLOG);
    float sn, c;
    __sincosf(f, &sn, &c);
    if (head < NQH) {
        const float* src = qkvf + (size_t)s * QKVN + head * DHEAD;
        float x1 = src[d], x2 = src[d + 64];
        unsigned short* dst = qb + ((size_t)head * SEQ + s) * DHEAD;
        dst[d]      = f2bf((x1 * c - x2 * sn) * SCALE);
        dst[d + 64] = f2bf((x2 * c + x1 * sn) * SCALE);
    } else {
        const int hk = head - NQH;
        const float* src = qkvf + (size_t)s * QKVN + 4096 + hk * DHEAD;
        float x1 = src[d], x2 = src[d + 64];
        unsigned short* dst = kb + ((size_t)hk * SEQ + s) * DHEAD;
        dst[d]      = f2bf(x1 * c - x2 * sn);
        dst[d + 64] = f2bf(x2 * c + x1 * sn);
    }
}

// ---------------- Flash attention ----------------
// T14 async-STAGE split: K/V global->reg loads for tile kb+1 issued before compute of kb,
// ds_writes happen after the barrier at the top of iteration kb+1.
__global__ __launch_bounds__(256) void attention_kernel(
    const unsigned short* __restrict__ Q, const unsigned short* __restrict__ K,
    const unsigned short* __restrict__ Vt, unsigned short* __restrict__ O) {
    __shared__ __align__(16) unsigned short Ks[64 * 128];    // [kcol][d], swizzled
    __shared__ __align__(16) unsigned short Vs[128 * 64];    // [d][k], swizzled
    __shared__ __align__(16) unsigned short Pl[4][16 * 64];  // per-wave [qr][k], swizzled
    const int h = blockIdx.x & 31;
    const int qb = (SEQ / 64 - 1) - (blockIdx.x >> 5);  // LPT: longest blocks first
    const int t = threadIdx.x, lane = t & 63, wave = t >> 6;
    const int r16 = lane & 15, kq = lane >> 4;
    const int q0 = qb * 64 + wave * 16;
    const int hkv = h >> 2;

    bf16x8 qfrag[4];
    const unsigned short* qrow = Q + ((size_t)h * SEQ + q0 + r16) * DHEAD;
    for (int c = 0; c < 4; c++) qfrag[c] = *(const bf16x8*)&qrow[c * 32 + kq * 8];

    f32x4 acc[8] = {};
    float m_r[4], l_r[4];
    for (int r = 0; r < 4; r++) { m_r[r] = -1e30f; l_r[r] = 0.f; }

    const unsigned short* Kg = K + (size_t)hkv * SEQ * DHEAD;
    const unsigned short* Vg = Vt + (size_t)hkv * DHEAD * SEQ;
    unsigned short* pw = &Pl[wave][0];

    const int krow = t >> 4, kch = t & 15;   // K staging: 4 rows/iter via +64
    const int vrow = t >> 3, vch = t & 7;    // V staging: 32 d-rows/iter via +32

    ushort8 kreg[4], vreg[4];
    #pragma unroll
    for (int p = 0; p < 4; p++) {
        kreg[p] = *(const ushort8*)&Kg[(size_t)(p * 16 + krow) * DHEAD + kch * 8];
        vreg[p] = *(const ushort8*)&Vg[(size_t)(p * 32 + vrow) * SEQ + vch * 8];
    }

    for (int kb = 0; kb <= qb; ++kb) {
        __syncthreads();
        #pragma unroll
        for (int p = 0; p < 4; p++) {
            int row = p * 16 + krow;
            *(ushort8*)&Ks[row * 128 + ((kch ^ (row & 7)) * 8)] = kreg[p];
            int vr = p * 32 + vrow;
            *(ushort8*)&Vs[vr * 64 + ((vch ^ (vr & 7)) * 8)] = vreg[p];
        }
        if (kb < qb) {
            #pragma unroll
            for (int p = 0; p < 4; p++) {
                kreg[p] = *(const ushort8*)&Kg[(size_t)((kb + 1) * 64 + p * 16 + krow) * DHEAD + kch * 8];
                vreg[p] = *(const ushort8*)&Vg[(size_t)(p * 32 + vrow) * SEQ + (kb + 1) * 64 + vch * 8];
            }
        }
        __syncthreads();
        f32x4 sf[4];
        for (int ct = 0; ct < 4; ct++) {
            f32x4 s4 = {};
            int row = ct * 16 + r16;
            for (int c = 0; c < 4; c++) {
                int ch = (c * 4 + kq) ^ (row & 7);
                bf16x8 kf2 = *(const bf16x8*)&Ks[row * 128 + ch * 8];
                s4 = __builtin_amdgcn_mfma_f32_16x16x32_bf16(qfrag[c], kf2, s4, 0, 0, 0);
            }
            sf[ct] = s4;
        }
        if (kb == qb) {
            for (int r = 0; r < 4; r++) {
                int qg = q0 + kq * 4 + r;
                for (int ct = 0; ct < 4; ct++) {
                    int col = kb * 64 + ct * 16 + r16;
                    if (col > qg) sf[ct][r] = -1e30f;
                }
            }
        }
        for (int r = 0; r < 4; r++) {
            float mx = fmaxf(fmaxf(sf[0][r], sf[1][r]), fmaxf(sf[2][r], sf[3][r]));
            for (int off = 1; off < 16; off <<= 1) mx = fmaxf(mx, __shfl_xor(mx, off, 16));
            float mnew = fmaxf(m_r[r], mx);
            float scale = __expf(m_r[r] - mnew);
            float sum = 0.f;
            for (int ct = 0; ct < 4; ct++) {
                float p = __expf(sf[ct][r] - mnew);
                sf[ct][r] = p; sum += p;
            }
            for (int off = 1; off < 16; off <<= 1) sum += __shfl_xor(sum, off, 16);
            l_r[r] = l_r[r] * scale + sum;
            m_r[r] = mnew;
            for (int nt = 0; nt < 8; nt++) acc[nt][r] *= scale;
        }
        for (int ct = 0; ct < 4; ct++)
            for (int r = 0; r < 4; r++) {
                int prow = kq * 4 + r, col = ct * 16 + r16;
                int ch = (col >> 3) ^ (prow & 7);
                pw[prow * 64 + ch * 8 + (col & 7)] = f2bf(sf[ct][r]);
            }
        for (int k32 = 0; k32 < 2; k32++) {
            int pch = (k32 * 4 + kq) ^ (r16 & 7);
            bf16x8 pf = *(const bf16x8*)&pw[r16 * 64 + pch * 8];
            for (int nt = 0; nt < 8; nt++) {
                int vr2 = nt * 16 + r16;
                int vc2 = (k32 * 4 + kq) ^ (vr2 & 7);
                bf16x8 vfr = *(const bf16x8*)&Vs[vr2 * 64 + vc2 * 8];
                acc[nt] = __builtin_amdgcn_mfma_f32_16x16x32_bf16(pf, vfr, acc[nt], 0, 0, 0);
            }
        }
    }
    float invl[4];
    for (int r = 0; r < 4; r++) invl[r] = 1.0f / l_r[r];
    for (int nt = 0; nt < 8; nt++)
        for (int r = 0; r < 4; r++)
            O[(size_t)(q0 + kq * 4 + r) * HDIM + h * DHEAD + nt * 16 + r16] =
                f2bf(acc[nt][r] * invl[r]);
}

extern "C" void kernel_launch(void* const* d_in, const int* in_sizes, int n_in,
                              void* d_out, int out_size, void* d_ws, size_t ws_size,
                              hipStream_t stream) {
    const float* hs  = (const float*)d_in[0];
    const float* lnw = (const float*)d_in[1];
    const float* lnb = (const float*)d_in[2];
    const float* wq  = (const float*)d_in[3];
    const float* wk  = (const float*)d_in[4];
    const float* wv  = (const float*)d_in[5];
    const float* wo  = (const float*)d_in[6];
    float* out = (float*)d_out;

    char* ws = (char*)d_ws;
    size_t off = 0;
    auto alloc = [&](size_t bytes) {
        void* p = ws + off;
        off += (bytes + 255) & ~(size_t)255;
        return p;
    };
    unsigned short* xb   = (unsigned short*)alloc((size_t)SEQ * HDIM * 2);
    // wqT/wkT/wvT contiguous -> fused [6144][4096] B matrix
    unsigned short* wqT  = (unsigned short*)alloc((size_t)HDIM * (NQH * DHEAD) * 2);
    unsigned short* wkT  = (unsigned short*)alloc((size_t)HDIM * (NKVH * DHEAD) * 2);
    unsigned short* wvT  = (unsigned short*)alloc((size_t)HDIM * (NKVH * DHEAD) * 2);
    unsigned short* woT  = (unsigned short*)alloc((size_t)(NQH * DHEAD) * HDIM * 2);
    float* qkvf          = (float*)alloc((size_t)SEQ * QKVN * 4);
    unsigned short* qbuf = (unsigned short*)alloc((size_t)NQH * SEQ * DHEAD * 2);
    unsigned short* kbuf = (unsigned short*)alloc((size_t)NKVH * SEQ * DHEAD * 2);
    unsigned short* vbt  = (unsigned short*)alloc((size_t)NKVH * DHEAD * SEQ * 2);
    unsigned short* attnb = (unsigned short*)qkvf;  // reuse fused-fp32 region after rope/v-transpose

    dim3 tb(32, 8);
    transpose_convert<<<dim3(4096 / 32, 4096 / 32), tb, 0, stream>>>(wq, wqT, 4096, 4096);
    transpose_convert<<<dim3(1024 / 32, 4096 / 32), tb, 0, stream>>>(wk, wkT, 4096, 1024);
    transpose_convert<<<dim3(1024 / 32, 4096 / 32), tb, 0, stream>>>(wv, wvT, 4096, 1024);
    transpose_convert<<<dim3(4096 / 32, 4096 / 32), tb, 0, stream>>>(wo, woT, 4096, 4096);

    layernorm_kernel<<<SEQ, 256, 0, stream>>>(hs, lnw, lnb, xb);

    // fused QKV projection: [2048][4096] x [6144][4096]^T -> [2048][6144]
    gemm128<<<(2048 / 128) * (QKVN / 128), 256, 0, stream>>>(xb, wqT, qkvf, 2048, QKVN, 4096, QKVN / 128);

    rope_convert<<<dim3(SEQ, NQH + NKVH), 64, 0, stream>>>(qkvf, qbuf, kbuf);
    transpose_v<<<dim3(SEQ / 32, DHEAD / 32, NKVH), tb, 0, stream>>>(qkvf, vbt);

    attention_kernel<<<NQH * (SEQ / 64), 256, 0, stream>>>(qbuf, kbuf, vbt, attnb);

    gemm128<<<(2048 / 128) * (4096 / 128), 256, 0, stream>>>(attnb, woT, out, 2048, 4096, 4096, 4096 / 128);
}